// Round 5
// baseline (188.292 us; speedup 1.0000x reference)
//
#include <hip/hip_runtime.h>

// YOLOv7 P3 head (stride 8): B=16, A=3, NC=80, H=W=80.
// Input  (b, a*85, h, w) channel-major fp32.
// Output (b, a*h*w, 85)  fp32: [px,py,pw,ph,conf,cls*80].
//
// v6: barrier-free wave-private transpose. Evidence from v1-v5: dur pinned
// at ~63.5us (2.6 TB/s for 163MB DRAM traffic = 41% of copy ceiling),
// invariant to NT-vs-cached stores and load scheduling fences; VALUBusy 10%
// matches the instruction model; Little's law says only ~4KB of loads in
// flight per CU despite ~18 resident waves. Diagnosis: block-wide
// load/barrier/transform/barrier/store phases keep wave slots empty of
// outstanding loads ~60% of the time (lockstep convoys + block retire).
// Fix: each WAVE owns an 85ch x 16x tile with a private 5440B LDS slice.
// load (6x coalesced dwordx4) -> transform -> transposed LDS write ->
// lgkmcnt (same-wave dep, compiler-inserted) -> contiguous b128 read ->
// 6x contiguous 1KB stores. Zero __syncthreads. 256-thread blocks
// (4 waves), 4800 blocks, 7 blocks/CU (LDS 21760B) = 28 waves/CU at
// fully independent phases -> continuous memory issue.

#define A_     3
#define H_     80
#define W_     80
#define CH_    85              // 5 + 80 classes
#define HW_    (H_ * W_)       // 6400
#define XB_    16              // x extent per wave tile
#define QT_    (CH_ * XB_ / 4) // 340 f32x4 quads per tile
#define WAVES_ 4               // waves per block
#define TILEF_ (CH_ * XB_)     // 1360 floats per tile

typedef float f32x4 __attribute__((ext_vector_type(4)));

__device__ __forceinline__ float fast_sigmoid(float x) {
    return __builtin_amdgcn_rcpf(1.0f + __expf(-x));
}

__global__ __launch_bounds__(256) void yolo_head_kernel(
    const float* __restrict__ in,
    const float* __restrict__ anchors,
    float* __restrict__ out)
{
    __shared__ float lds[WAVES_ * TILEF_];   // 21760 B

    const int t = threadIdx.x;
    const int w = t >> 6;          // wave 0..3
    const int l = t & 63;          // lane

    // global wave-tile id: 19200 tiles = (ba,y,xb), xb fastest
    const int g   = blockIdx.x * WAVES_ + w;
    const int xb  = g % 5;
    const int rem = g / 5;
    const int y   = rem % H_;
    const int ba  = rem / H_;      // b*3 + a, 0..47
    const int a   = ba % A_;
    const int x0  = xb * XB_;

    const float aw = anchors[2 * a];
    const float ah = anchors[2 * a + 1];
    const float fy = (float)y;

    // ---- Load: 6 coalesced f32x4 per lane (quad q = ch*4 + xq) ----
    // in[(ba*85 + ch)*6400 + y*80 + x0 + 4*xq + j]
    const float* in_base = in + (size_t)(ba * CH_) * HW_ + y * W_ + x0;

    f32x4 v[6];
#pragma unroll
    for (int k = 0; k < 6; ++k) {
        int q  = k * 64 + l;
        int qc = (q < QT_) ? q : (QT_ - 1);   // clamp: valid addr re-load
        int ch = qc >> 2;
        int xq = qc & 3;
        v[k] = *(const f32x4*)(in_base + ch * HW_ + 4 * xq);
    }
    __builtin_amdgcn_sched_barrier(0);

    // ---- Transform -> wave-private LDS, transposed [16 x][85 ch] ----
    float* wlds = lds + w * TILEF_;
#pragma unroll
    for (int k = 0; k < 6; ++k) {
        int q = k * 64 + l;
        if (q < QT_) {
            int ch = q >> 2;
            int xq = q & 3;
            f32x4 d = v[k];
            float r[4];
            if (ch >= 4) {
                r[0] = fast_sigmoid(d.x);
                r[1] = fast_sigmoid(d.y);
                r[2] = fast_sigmoid(d.z);
                r[3] = fast_sigmoid(d.w);
            } else if (ch == 0) {
                float xg = (float)(x0 + 4 * xq);
                r[0] = (fast_sigmoid(d.x) + xg)        * 8.0f;  // px
                r[1] = (fast_sigmoid(d.y) + xg + 1.0f) * 8.0f;
                r[2] = (fast_sigmoid(d.z) + xg + 2.0f) * 8.0f;
                r[3] = (fast_sigmoid(d.w) + xg + 3.0f) * 8.0f;
            } else if (ch == 1) {
                r[0] = (fast_sigmoid(d.x) + fy) * 8.0f;         // py
                r[1] = (fast_sigmoid(d.y) + fy) * 8.0f;
                r[2] = (fast_sigmoid(d.z) + fy) * 8.0f;
                r[3] = (fast_sigmoid(d.w) + fy) * 8.0f;
            } else {
                float s = (ch == 2) ? aw : ah;                  // pw / ph
                r[0] = __expf(fminf(fmaxf(d.x, -16.0f), 16.0f)) * s;
                r[1] = __expf(fminf(fmaxf(d.y, -16.0f), 16.0f)) * s;
                r[2] = __expf(fminf(fmaxf(d.z, -16.0f), 16.0f)) * s;
                r[3] = __expf(fminf(fmaxf(d.w, -16.0f), 16.0f)) * s;
            }
            int base = 4 * xq * CH_ + ch;    // wlds[(4*xq+j)*85 + ch]
#pragma unroll
            for (int j = 0; j < 4; ++j)
                wlds[base + j * CH_] = r[j];
        }
    }
    // same-wave LDS dependency: compiler inserts s_waitcnt lgkmcnt(0);
    // no __syncthreads needed (tile is wave-private).

    // ---- Contiguous LDS read -> contiguous global stores ----
    // out tile base: ((ba*6400 + y*80 + x0) * 85) floats, 1360 contiguous.
    f32x4*       out4 = (f32x4*)(out + (size_t)(ba * HW_ + y * W_ + x0) * CH_);
    const f32x4* l4   = (const f32x4*)wlds;

    f32x4 o[6];
#pragma unroll
    for (int k = 0; k < 6; ++k) {
        int q  = k * 64 + l;
        int qc = (q < QT_) ? q : (QT_ - 1);
        o[k] = l4[qc];
    }
    __builtin_amdgcn_sched_barrier(0);
#pragma unroll
    for (int k = 0; k < 6; ++k) {
        int q = k * 64 + l;
        if (q < QT_) {
            out4[q] = o[k];
        }
    }
}

extern "C" void kernel_launch(void* const* d_in, const int* in_sizes, int n_in,
                              void* d_out, int out_size, void* d_ws, size_t ws_size,
                              hipStream_t stream) {
    const float* in      = (const float*)d_in[0];   // (16, 255, 80, 80) fp32
    const float* anchors = (const float*)d_in[1];   // (3, 2) fp32
    float*       out     = (float*)d_out;           // (16, 19200, 85) fp32

    // 19200 wave tiles / 4 waves per block
    const int blocks = 16 * A_ * H_ * (W_ / XB_) / WAVES_;   // 4800
    yolo_head_kernel<<<blocks, 256, 0, stream>>>(in, anchors, out);
}

// Round 6
// 185.045 us; speedup vs baseline: 1.0175x; 1.0175x over previous
//
#include <hip/hip_runtime.h>

// YOLOv7 P3 head (stride 8): B=16, A=3, NC=80, H=W=80.
// Input  (b, a*85, h, w) channel-major fp32.
// Output (b, a*h*w, 85)  fp32: [px,py,pw,ph,conf,cls*80].
//
// v7: y-pair blocks -> 640B read segments. Evidence trail: v1-v6 pinned at
// 2.3-2.7 TB/s for ~160MB compulsory DRAM traffic with no CU pipe >15%
// busy; MLP refuted (v6: 6 loads in flight, slightly slower); store policy
// refuted (v5 == v4 == v1). Only dose-response found: read segment size
// (320B -> 64B cost 12% BW). Input rows y,y+1 are contiguous per channel
// plane, so a block covering a y-PAIR reads 85 channels x 640B contiguous
// segments -- 2x the contiguity at identical traffic.
// Block = (ba, y/2): 1920 blocks, 512 threads, LDS 54.4KB (2 blocks/CU,
// 16 waves/CU). Load 7x clamped f32x4/thread + fence; transform; transposed
// LDS scalar writes; barrier; contiguous b128 reads -> 27.2KB contiguous
// cached stores per block.

#define A_     3
#define H_     80
#define W_     80
#define CH_    85                   // 5 + 80 classes
#define HW_    (H_ * W_)            // 6400
#define YPB_   2                    // y rows per block
#define TILEF_ (CH_ * W_ * YPB_)    // 13600 floats
#define QT_    (TILEF_ / 4)         // 3400 f32x4 quads
#define NIT_   7                    // ceil(3400 / 512)

typedef float f32x4 __attribute__((ext_vector_type(4)));

__device__ __forceinline__ float fast_sigmoid(float x) {
    return __builtin_amdgcn_rcpf(1.0f + __expf(-x));
}

__global__ __launch_bounds__(512) void yolo_head_kernel(
    const float* __restrict__ in,
    const float* __restrict__ anchors,
    float* __restrict__ out)
{
    __shared__ float lds[TILEF_];   // 54400 B

    const int bid = blockIdx.x;        // ba*40 + y2
    const int y2  = bid % (H_ / YPB_);
    const int ba  = bid / (H_ / YPB_); // b*3 + a
    const int a   = ba % A_;
    const int y0  = y2 * YPB_;

    const float aw = anchors[2 * a];
    const float ah = anchors[2 * a + 1];
    const int   t  = threadIdx.x;

    // ---- Phase 1a: 7 clamped f32x4 loads, 640B segments ----
    // quad i = ch*40 + xq, xq in [0,40): 160 floats = rows y0,y0+1 of ch.
    const float* in_base = in + (size_t)(ba * CH_) * HW_ + y0 * W_;

    f32x4 v[NIT_];
#pragma unroll
    for (int k = 0; k < NIT_; ++k) {
        int i = k * 512 + t;
        i = (i < QT_) ? i : (QT_ - 1);   // clamp: tail lanes re-load last quad
        int ch = i / 40;
        int xq = i - ch * 40;
        v[k] = *(const f32x4*)(in_base + ch * HW_ + 4 * xq);
    }
    __builtin_amdgcn_sched_barrier(0);

    // ---- Phase 1b: transform -> LDS transposed [2 rows][80 x][85 ch] ----
#pragma unroll
    for (int k = 0; k < NIT_; ++k) {
        int i = k * 512 + t;
        if (i < QT_) {
            int ch = i / 40;
            int xq = i - ch * 40;
            int r  = (xq >= 20);             // quads don't straddle rows (80%4==0)
            int xb = 4 * xq - 80 * r;        // x of elem j: xb + j
            f32x4 d = v[k];
            float rr[4];
            if (ch >= 4) {
                rr[0] = fast_sigmoid(d.x);
                rr[1] = fast_sigmoid(d.y);
                rr[2] = fast_sigmoid(d.z);
                rr[3] = fast_sigmoid(d.w);
            } else if (ch == 0) {
                float xg = (float)xb;
                rr[0] = (fast_sigmoid(d.x) + xg)        * 8.0f;  // px
                rr[1] = (fast_sigmoid(d.y) + xg + 1.0f) * 8.0f;
                rr[2] = (fast_sigmoid(d.z) + xg + 2.0f) * 8.0f;
                rr[3] = (fast_sigmoid(d.w) + xg + 3.0f) * 8.0f;
            } else if (ch == 1) {
                float fy = (float)(y0 + r);
                rr[0] = (fast_sigmoid(d.x) + fy) * 8.0f;         // py
                rr[1] = (fast_sigmoid(d.y) + fy) * 8.0f;
                rr[2] = (fast_sigmoid(d.z) + fy) * 8.0f;
                rr[3] = (fast_sigmoid(d.w) + fy) * 8.0f;
            } else {
                float s = (ch == 2) ? aw : ah;                   // pw / ph
                rr[0] = __expf(fminf(fmaxf(d.x, -16.0f), 16.0f)) * s;
                rr[1] = __expf(fminf(fmaxf(d.y, -16.0f), 16.0f)) * s;
                rr[2] = __expf(fminf(fmaxf(d.z, -16.0f), 16.0f)) * s;
                rr[3] = __expf(fminf(fmaxf(d.w, -16.0f), 16.0f)) * s;
            }
            // lds[r*6800 + (xb+j)*85 + ch]
            int base = r * (CH_ * W_) + xb * CH_ + ch;
#pragma unroll
            for (int j = 0; j < 4; ++j)
                lds[base + j * CH_] = rr[j];
        }
    }
    __syncthreads();

    // ---- Phase 2: contiguous LDS read -> 27.2KB contiguous cached stores ----
    // out base: (ba*6400 + y0*80) * 85 floats; 13600 floats contiguous.
    f32x4*       out4 = (f32x4*)(out + (size_t)(ba * HW_ + y0 * W_) * CH_);
    const f32x4* lds4 = (const f32x4*)lds;

    f32x4 o[NIT_];
#pragma unroll
    for (int k = 0; k < NIT_; ++k) {
        int c = k * 512 + t;
        c = (c < QT_) ? c : (QT_ - 1);
        o[k] = lds4[c];
    }
    __builtin_amdgcn_sched_barrier(0);
#pragma unroll
    for (int k = 0; k < NIT_; ++k) {
        int c = k * 512 + t;
        if (c < QT_) {
            out4[c] = o[k];
        }
    }
}

extern "C" void kernel_launch(void* const* d_in, const int* in_sizes, int n_in,
                              void* d_out, int out_size, void* d_ws, size_t ws_size,
                              hipStream_t stream) {
    const float* in      = (const float*)d_in[0];   // (16, 255, 80, 80) fp32
    const float* anchors = (const float*)d_in[1];   // (3, 2) fp32
    float*       out     = (float*)d_out;           // (16, 19200, 85) fp32

    const int blocks = 16 * A_ * (H_ / YPB_);       // 1920: one per (b,a,y-pair)
    yolo_head_kernel<<<blocks, 512, 0, stream>>>(in, anchors, out);
}